// Round 1
// baseline (3081.460 us; speedup 1.0000x reference)
//
#include <hip/hip_runtime.h>
#include <hip/hip_bf16.h>
#include <math.h>

#define D_MODEL 512
#define NHEAD 4
#define HDIM 128
#define BATCH 4

// ---------------------------------------------------------------------------
// boundary prefix scan -> segment start table
// grid.x = B, block = 1024
__global__ __launch_bounds__(1024) void scan_bounds_kernel(
    const int* __restrict__ bnd, int* __restrict__ starts, int n, int nseg) {
  __shared__ int sums[1024];
  int row = blockIdx.x;
  const int* br = bnd + (size_t)row * n;
  int chunk = (n + 1023) / 1024;
  int t0 = threadIdx.x * chunk;
  int t1 = t0 + chunk; if (t1 > n) t1 = n;
  int s = 0;
  for (int t = t0; t < t1; ++t) s += br[t];
  sums[threadIdx.x] = s;
  __syncthreads();
  for (int off = 1; off < 1024; off <<= 1) {
    int v = (threadIdx.x >= off) ? sums[threadIdx.x - off] : 0;
    __syncthreads();
    sums[threadIdx.x] += v;
    __syncthreads();
  }
  int run = sums[threadIdx.x] - s;  // exclusive prefix of ones
  for (int t = t0; t < t1; ++t) {
    if (br[t]) { starts[(size_t)row * nseg + run] = t; ++run; }
  }
}

// ---------------------------------------------------------------------------
// segment mean pool. grid = (nseg, B), block = 128 (each thread 4 dims)
__global__ __launch_bounds__(128) void pool_kernel(
    const float* __restrict__ x, const int* __restrict__ starts,
    float* __restrict__ y, int Tin, int nseg) {
  int s = blockIdx.x, b = blockIdx.y;
  int st = starts[(size_t)b * nseg + s];
  int en = (s + 1 < nseg) ? starts[(size_t)b * nseg + s + 1] : Tin;
  const float* xb = x + (size_t)b * Tin * D_MODEL;
  int d = threadIdx.x * 4;
  float4 acc = make_float4(0.f, 0.f, 0.f, 0.f);
  for (int t = st; t < en; ++t) {
    float4 v = *(const float4*)(xb + (size_t)t * D_MODEL + d);
    acc.x += v.x; acc.y += v.y; acc.z += v.z; acc.w += v.w;
  }
  int cnt = en - st; if (cnt < 1) cnt = 1;
  float inv = 1.0f / (float)cnt;
  float4 r = make_float4(acc.x * inv, acc.y * inv, acc.z * inv, acc.w * inv);
  *(float4*)(y + ((size_t)b * nseg + s) * D_MODEL + d) = r;
}

// ---------------------------------------------------------------------------
// LayerNorm: one wave (64 lanes) per token, 8 floats/lane. block=256 (4 tokens)
__global__ __launch_bounds__(256) void ln_kernel(
    const float* __restrict__ x, const float* __restrict__ g,
    const float* __restrict__ bt, float* __restrict__ y, int ntok) {
  int wave = threadIdx.x >> 6, lane = threadIdx.x & 63;
  int tok = blockIdx.x * 4 + wave;
  if (tok >= ntok) return;
  const float* xr = x + (size_t)tok * D_MODEL;
  int d = lane * 8;
  float4 v0 = *(const float4*)(xr + d);
  float4 v1 = *(const float4*)(xr + d + 4);
  float s = v0.x + v0.y + v0.z + v0.w + v1.x + v1.y + v1.z + v1.w;
  #pragma unroll
  for (int off = 32; off; off >>= 1) s += __shfl_xor(s, off, 64);
  float mean = s * (1.0f / 512.0f);
  float a0 = v0.x - mean, a1 = v0.y - mean, a2 = v0.z - mean, a3 = v0.w - mean;
  float a4 = v1.x - mean, a5 = v1.y - mean, a6 = v1.z - mean, a7 = v1.w - mean;
  float ss = a0*a0 + a1*a1 + a2*a2 + a3*a3 + a4*a4 + a5*a5 + a6*a6 + a7*a7;
  #pragma unroll
  for (int off = 32; off; off >>= 1) ss += __shfl_xor(ss, off, 64);
  float inv = rsqrtf(ss * (1.0f / 512.0f) + 1e-5f);
  float4 g0 = *(const float4*)(g + d), g1 = *(const float4*)(g + d + 4);
  float4 b0 = *(const float4*)(bt + d), b1 = *(const float4*)(bt + d + 4);
  float4 r0, r1;
  r0.x = a0 * inv * g0.x + b0.x; r0.y = a1 * inv * g0.y + b0.y;
  r0.z = a2 * inv * g0.z + b0.z; r0.w = a3 * inv * g0.w + b0.w;
  r1.x = a4 * inv * g1.x + b1.x; r1.y = a5 * inv * g1.y + b1.y;
  r1.z = a6 * inv * g1.z + b1.z; r1.w = a7 * inv * g1.w + b1.w;
  float* yr = y + (size_t)tok * D_MODEL;
  *(float4*)(yr + d) = r0;
  *(float4*)(yr + d + 4) = r1;
}

// ---------------------------------------------------------------------------
// fp32 tiled GEMM: C[N,M] = op(A[N,K] @ W[K,M] + bias)  (+= if doRes)
// tile 64x64x16, block 256, thread tile 4x4. All dims multiples of 64/16.
__device__ __forceinline__ float gelu_exact(float x) {
  return 0.5f * x * (1.0f + erff(x * 0.70710678118654752f));
}

__global__ __launch_bounds__(256) void gemm_kernel(
    const float* __restrict__ A, const float* __restrict__ W,
    const float* __restrict__ bias, float* __restrict__ C,
    int N, int K, int M, int doGelu, int doRes) {
  __shared__ float As[16][64];
  __shared__ float Ws[16][64];
  int n0 = blockIdx.y * 64, m0 = blockIdx.x * 64;
  int tid = threadIdx.x;
  int tx = tid & 15, ty = tid >> 4;
  int ar = tid >> 2;            // 0..63
  int ak = (tid & 3) * 4;       // 0,4,8,12
  int wk = tid >> 4;            // 0..15
  int wm = (tid & 15) * 4;
  const float* Aptr = A + (size_t)(n0 + ar) * K + ak;
  const float* Wptr = W + (size_t)wk * M + m0 + wm;
  float acc[4][4] = {};
  for (int k0 = 0; k0 < K; k0 += 16) {
    float4 av = *(const float4*)(Aptr + k0);
    float4 wv = *(const float4*)(Wptr + (size_t)k0 * M);
    As[ak + 0][ar] = av.x; As[ak + 1][ar] = av.y;
    As[ak + 2][ar] = av.z; As[ak + 3][ar] = av.w;
    *(float4*)&Ws[wk][wm] = wv;
    __syncthreads();
    #pragma unroll
    for (int kk = 0; kk < 16; ++kk) {
      float4 a = *(const float4*)&As[kk][ty * 4];
      float4 w = *(const float4*)&Ws[kk][tx * 4];
      acc[0][0] += a.x * w.x; acc[0][1] += a.x * w.y; acc[0][2] += a.x * w.z; acc[0][3] += a.x * w.w;
      acc[1][0] += a.y * w.x; acc[1][1] += a.y * w.y; acc[1][2] += a.y * w.z; acc[1][3] += a.y * w.w;
      acc[2][0] += a.z * w.x; acc[2][1] += a.z * w.y; acc[2][2] += a.z * w.z; acc[2][3] += a.z * w.w;
      acc[3][0] += a.w * w.x; acc[3][1] += a.w * w.y; acc[3][2] += a.w * w.z; acc[3][3] += a.w * w.w;
    }
    __syncthreads();
  }
  float4 bv = *(const float4*)(bias + m0 + tx * 4);
  #pragma unroll
  for (int i = 0; i < 4; ++i) {
    int row = n0 + ty * 4 + i;
    float* cp = C + (size_t)row * M + m0 + tx * 4;
    float4 r;
    r.x = acc[i][0] + bv.x; r.y = acc[i][1] + bv.y;
    r.z = acc[i][2] + bv.z; r.w = acc[i][3] + bv.w;
    if (doGelu) {
      r.x = gelu_exact(r.x); r.y = gelu_exact(r.y);
      r.z = gelu_exact(r.z); r.w = gelu_exact(r.w);
    }
    if (doRes) {
      float4 old = *(const float4*)cp;
      r.x += old.x; r.y += old.y; r.z += old.z; r.w += old.w;
    }
    *(float4*)cp = r;
  }
}

// ---------------------------------------------------------------------------
// attention: one block per (q, head, batch). block=256. Skv <= 1024, even.
__global__ __launch_bounds__(256) void attn_kernel(
    const float* __restrict__ q, const float* __restrict__ k,
    const float* __restrict__ v, float* __restrict__ o, int Sq, int Skv) {
  __shared__ float qs[HDIM];
  __shared__ float att[1024];
  __shared__ float red[256];
  __shared__ float part[HDIM];
  int qi = blockIdx.x, h = blockIdx.y, b = blockIdx.z;
  int tid = threadIdx.x;
  const float scale = 0.08838834764831845f;  // 1/sqrt(128)
  const float* qr = q + ((size_t)(b * Sq + qi)) * D_MODEL + h * HDIM;
  if (tid < HDIM) qs[tid] = qr[tid];
  __syncthreads();
  float lmax = -1e30f;
  for (int j = tid; j < Skv; j += 256) {
    const float* kr = k + ((size_t)(b * Skv + j)) * D_MODEL + h * HDIM;
    float s = 0.f;
    #pragma unroll
    for (int d = 0; d < HDIM; d += 4) {
      float4 kq = *(const float4*)(kr + d);
      float4 qq = *(const float4*)(qs + d);
      s += qq.x * kq.x + qq.y * kq.y + qq.z * kq.z + qq.w * kq.w;
    }
    s *= scale;
    att[j] = s;
    lmax = fmaxf(lmax, s);
  }
  red[tid] = lmax;
  __syncthreads();
  for (int off = 128; off; off >>= 1) {
    if (tid < off) red[tid] = fmaxf(red[tid], red[tid + off]);
    __syncthreads();
  }
  float mx = red[0];
  __syncthreads();
  float lsum = 0.f;
  for (int j = tid; j < Skv; j += 256) {
    float e = __expf(att[j] - mx);
    att[j] = e;
    lsum += e;
  }
  red[tid] = lsum;
  __syncthreads();
  for (int off = 128; off; off >>= 1) {
    if (tid < off) red[tid] += red[tid + off];
    __syncthreads();
  }
  float inv = 1.0f / red[0];
  __syncthreads();
  int d = tid & 127, half = tid >> 7;
  int jn = Skv >> 1;
  int j0 = half * jn, j1 = j0 + jn;
  float acc = 0.f;
  for (int j = j0; j < j1; ++j)
    acc += att[j] * v[((size_t)(b * Skv + j)) * D_MODEL + h * HDIM + d];
  if (half) part[d] = acc;
  __syncthreads();
  if (!half)
    o[((size_t)(b * Sq + qi)) * D_MODEL + h * HDIM + d] = (acc + part[d]) * inv;
}

// ---------------------------------------------------------------------------
extern "C" void kernel_launch(void* const* d_in, const int* in_sizes, int n_in,
                              void* d_out, int out_size, void* d_ws, size_t ws_size,
                              hipStream_t stream) {
  (void)in_sizes; (void)n_in; (void)out_size; (void)ws_size;
  const float* h_bytes  = (const float*)d_in[0];
  const int*   b0       = (const int*)d_in[1];
  const int*   b1       = (const int*)d_in[2];
  const int*   b2       = (const int*)d_in[3];
  const float* mlp_ln_g = (const float*)d_in[4];
  const float* mlp_ln_b = (const float*)d_in[5];
  const float* mlp_w1   = (const float*)d_in[6];
  const float* mlp_b1   = (const float*)d_in[7];
  const float* mlp_w2   = (const float*)d_in[8];
  const float* mlp_b2   = (const float*)d_in[9];
  const float* ca_w     = (const float*)d_in[10];
  const float* ca_b     = (const float*)d_in[11];
  const float* ca_ln_g  = (const float*)d_in[12];
  const float* ca_ln_b  = (const float*)d_in[13];

  float* out0 = (float*)d_out;                 // 4*1024*512
  float* out1 = out0 + 4 * 1024 * 512;         // 4*256*512
  float* out2 = out1 + 4 * 256 * 512;          // 4*64*512

  float* ws    = (float*)d_ws;
  float* lnbuf = ws;                 // 2097152 floats
  float* qbuf  = ws + 2097152;       // 2097152
  float* kbuf  = ws + 4194304;       // 2097152
  float* vbuf  = ws + 6291456;       // 2097152
  float* hbuf  = ws + 2097152;       // 4194304 (overlaps q/k; MLP phase only)
  float* abuf  = lnbuf;              // reuse (ln consumed before attn writes)
  int* starts0 = (int*)(ws + 8388608);
  int* starts1 = starts0 + 4 * 1024;
  int* starts2 = starts1 + 4 * 256;

  // segment start tables
  scan_bounds_kernel<<<4, 1024, 0, stream>>>(b0, starts0, 8192, 1024);
  scan_bounds_kernel<<<4, 1024, 0, stream>>>(b1, starts1, 1024, 256);
  scan_bounds_kernel<<<4, 1024, 0, stream>>>(b2, starts2, 256, 64);

  // ---- level 0: pool 8192->1024, MLP
  pool_kernel<<<dim3(1024, 4), 128, 0, stream>>>(h_bytes, starts0, out0, 8192, 1024);
  ln_kernel<<<1024, 256, 0, stream>>>(out0, mlp_ln_g, mlp_ln_b, lnbuf, 4096);
  gemm_kernel<<<dim3(16, 64), 256, 0, stream>>>(lnbuf, mlp_w1, mlp_b1, hbuf, 4096, 512, 1024, 1, 0);
  gemm_kernel<<<dim3(8, 64), 256, 0, stream>>>(hbuf, mlp_w2, mlp_b2, out0, 4096, 1024, 512, 0, 1);

  // ---- level 1: pool 1024->256, MLP
  pool_kernel<<<dim3(256, 4), 128, 0, stream>>>(out0, starts1, out1, 1024, 256);
  ln_kernel<<<256, 256, 0, stream>>>(out1, mlp_ln_g + 512, mlp_ln_b + 512, lnbuf, 1024);
  gemm_kernel<<<dim3(16, 16), 256, 0, stream>>>(lnbuf, mlp_w1 + 512 * 1024, mlp_b1 + 1024, hbuf, 1024, 512, 1024, 1, 0);
  gemm_kernel<<<dim3(8, 16), 256, 0, stream>>>(hbuf, mlp_w2 + 1024 * 512, mlp_b2 + 512, out1, 1024, 1024, 512, 0, 1);

  // ---- level 2: pool 256->64, MLP
  pool_kernel<<<dim3(64, 4), 128, 0, stream>>>(out1, starts2, out2, 256, 64);
  ln_kernel<<<64, 256, 0, stream>>>(out2, mlp_ln_g + 1024, mlp_ln_b + 1024, lnbuf, 256);
  gemm_kernel<<<dim3(16, 4), 256, 0, stream>>>(lnbuf, mlp_w1 + 2 * 512 * 1024, mlp_b1 + 2048, hbuf, 256, 512, 1024, 1, 0);
  gemm_kernel<<<dim3(8, 4), 256, 0, stream>>>(hbuf, mlp_w2 + 2 * 1024 * 512, mlp_b2 + 1024, out2, 256, 1024, 512, 0, 1);

  // ---- cross-level refinement
  auto cross = [&](int i, float* F, float* Cc, int nf, int nc) {
    const size_t WS = (size_t)512 * 512;
    const float* w  = ca_w + (size_t)i * 8 * WS;
    const float* bb = ca_b + (size_t)i * 8 * 512;
    const float* lg = ca_ln_g + (size_t)i * 2 * 512;
    const float* lb = ca_ln_b + (size_t)i * 2 * 512;
    int Nf = BATCH * nf, Nc = BATCH * nc;
    // bottom-up: fine queries attend to coarse
    ln_kernel<<<Nf / 4, 256, 0, stream>>>(F, lg, lb, lnbuf, Nf);
    gemm_kernel<<<dim3(8, Nf / 64), 256, 0, stream>>>(lnbuf, w, bb, qbuf, Nf, 512, 512, 0, 0);
    gemm_kernel<<<dim3(8, Nc / 64), 256, 0, stream>>>(Cc, w + WS, bb + 512, kbuf, Nc, 512, 512, 0, 0);
    gemm_kernel<<<dim3(8, Nc / 64), 256, 0, stream>>>(Cc, w + 2 * WS, bb + 2 * 512, vbuf, Nc, 512, 512, 0, 0);
    attn_kernel<<<dim3(nf, NHEAD, BATCH), 256, 0, stream>>>(qbuf, kbuf, vbuf, abuf, nf, nc);
    gemm_kernel<<<dim3(8, Nf / 64), 256, 0, stream>>>(abuf, w + 3 * WS, bb + 3 * 512, F, Nf, 512, 512, 0, 1);
    // top-down: coarse queries attend to updated fine
    ln_kernel<<<Nc / 4, 256, 0, stream>>>(Cc, lg + 512, lb + 512, lnbuf, Nc);
    gemm_kernel<<<dim3(8, Nc / 64), 256, 0, stream>>>(lnbuf, w + 4 * WS, bb + 4 * 512, qbuf, Nc, 512, 512, 0, 0);
    gemm_kernel<<<dim3(8, Nf / 64), 256, 0, stream>>>(F, w + 5 * WS, bb + 5 * 512, kbuf, Nf, 512, 512, 0, 0);
    gemm_kernel<<<dim3(8, Nf / 64), 256, 0, stream>>>(F, w + 6 * WS, bb + 6 * 512, vbuf, Nf, 512, 512, 0, 0);
    attn_kernel<<<dim3(nc, NHEAD, BATCH), 256, 0, stream>>>(qbuf, kbuf, vbuf, abuf, nc, nf);
    gemm_kernel<<<dim3(8, Nc / 64), 256, 0, stream>>>(abuf, w + 7 * WS, bb + 7 * 512, Cc, Nc, 512, 512, 0, 1);
  };
  cross(1, out1, out2, 256, 64);
  cross(0, out0, out1, 1024, 256);
}

// Round 2
// 516.687 us; speedup vs baseline: 5.9639x; 5.9639x over previous
//
#include <hip/hip_runtime.h>
#include <hip/hip_bf16.h>
#include <math.h>

#define NHEAD 4

typedef __attribute__((ext_vector_type(8))) short bf16x8;
typedef __attribute__((ext_vector_type(4))) float f32x4;
typedef unsigned short u16;

__device__ __forceinline__ u16 f2b(float f) {
  unsigned u = __float_as_uint(f);
  u = u + 0x7fffu + ((u >> 16) & 1u);   // round-to-nearest-even
  return (u16)(u >> 16);
}
__device__ __forceinline__ float gelu_exact(float x) {
  return 0.5f * x * (1.0f + erff(x * 0.70710678118654752f));
}

// ---------------------------------------------------------------------------
// boundary prefix scan -> segment start table. grid.x = B, block = 1024
__global__ __launch_bounds__(1024) void scan_bounds_kernel(
    const int* __restrict__ bnd, int* __restrict__ starts, int n, int nseg) {
  __shared__ int sums[1024];
  int row = blockIdx.x;
  const int* br = bnd + (size_t)row * n;
  int chunk = (n + 1023) / 1024;
  int t0 = threadIdx.x * chunk;
  int t1 = t0 + chunk; if (t1 > n) t1 = n;
  int s = 0;
  for (int t = t0; t < t1; ++t) s += br[t];
  sums[threadIdx.x] = s;
  __syncthreads();
  for (int off = 1; off < 1024; off <<= 1) {
    int v = (threadIdx.x >= off) ? sums[threadIdx.x - off] : 0;
    __syncthreads();
    sums[threadIdx.x] += v;
    __syncthreads();
  }
  int run = sums[threadIdx.x] - s;
  for (int t = t0; t < t1; ++t) {
    if (br[t]) { starts[(size_t)row * nseg + run] = t; ++run; }
  }
}

// ---------------------------------------------------------------------------
// segment mean pool. grid = (nseg, B), block = 128
__global__ __launch_bounds__(128) void pool_kernel(
    const float* __restrict__ x, const int* __restrict__ starts,
    float* __restrict__ y, int Tin, int nseg) {
  int s = blockIdx.x, b = blockIdx.y;
  int st = starts[(size_t)b * nseg + s];
  int en = (s + 1 < nseg) ? starts[(size_t)b * nseg + s + 1] : Tin;
  const float* xb = x + (size_t)b * Tin * 512;
  int d = threadIdx.x * 4;
  float4 acc = make_float4(0.f, 0.f, 0.f, 0.f);
  for (int t = st; t < en; ++t) {
    float4 v = *(const float4*)(xb + (size_t)t * 512 + d);
    acc.x += v.x; acc.y += v.y; acc.z += v.z; acc.w += v.w;
  }
  int cnt = en - st; if (cnt < 1) cnt = 1;
  float inv = 1.0f / (float)cnt;
  *(float4*)(y + ((size_t)b * nseg + s) * 512 + d) =
      make_float4(acc.x * inv, acc.y * inv, acc.z * inv, acc.w * inv);
}

// ---------------------------------------------------------------------------
// LayerNorm fp32 in -> bf16 out. one wave per token, block=256 (4 tokens)
__global__ __launch_bounds__(256) void ln_kernel(
    const float* __restrict__ x, const float* __restrict__ g,
    const float* __restrict__ bt, u16* __restrict__ y, int ntok) {
  int wave = threadIdx.x >> 6, lane = threadIdx.x & 63;
  int tok = blockIdx.x * 4 + wave;
  if (tok >= ntok) return;
  const float* xr = x + (size_t)tok * 512;
  int d = lane * 8;
  float4 v0 = *(const float4*)(xr + d);
  float4 v1 = *(const float4*)(xr + d + 4);
  float s = v0.x + v0.y + v0.z + v0.w + v1.x + v1.y + v1.z + v1.w;
  #pragma unroll
  for (int off = 32; off; off >>= 1) s += __shfl_xor(s, off, 64);
  float mean = s * (1.0f / 512.0f);
  float a[8] = {v0.x-mean, v0.y-mean, v0.z-mean, v0.w-mean,
                v1.x-mean, v1.y-mean, v1.z-mean, v1.w-mean};
  float ss = 0.f;
  #pragma unroll
  for (int i = 0; i < 8; ++i) ss += a[i]*a[i];
  #pragma unroll
  for (int off = 32; off; off >>= 1) ss += __shfl_xor(ss, off, 64);
  float inv = rsqrtf(ss * (1.0f / 512.0f) + 1e-5f);
  float4 g0 = *(const float4*)(g + d), g1 = *(const float4*)(g + d + 4);
  float4 b0 = *(const float4*)(bt + d), b1 = *(const float4*)(bt + d + 4);
  float gg[8] = {g0.x,g0.y,g0.z,g0.w,g1.x,g1.y,g1.z,g1.w};
  float bb[8] = {b0.x,b0.y,b0.z,b0.w,b1.x,b1.y,b1.z,b1.w};
  union { u16 u[8]; uint4 v; } pk;
  #pragma unroll
  for (int i = 0; i < 8; ++i) pk.u[i] = f2b(a[i] * inv * gg[i] + bb[i]);
  *(uint4*)(y + (size_t)tok * 512 + d) = pk.v;
}

// ---------------------------------------------------------------------------
// flat fp32 -> bf16 cast, 8 elems/thread
__global__ __launch_bounds__(256) void castbf_kernel(
    const float* __restrict__ x, u16* __restrict__ y, int n8) {
  int i = blockIdx.x * 256 + threadIdx.x;
  if (i >= n8) return;
  float4 v0 = *(const float4*)(x + (size_t)i * 8);
  float4 v1 = *(const float4*)(x + (size_t)i * 8 + 4);
  float a[8] = {v0.x,v0.y,v0.z,v0.w,v1.x,v1.y,v1.z,v1.w};
  union { u16 u[8]; uint4 v; } pk;
  #pragma unroll
  for (int j = 0; j < 8; ++j) pk.u[j] = f2b(a[j]);
  *(uint4*)(y + (size_t)i * 8) = pk.v;
}

// ---------------------------------------------------------------------------
// weight cast + transpose: W fp32 [K,M] -> Wt bf16 [M,K]. grid (M/32,K/32,cnt)
__global__ __launch_bounds__(256) void wtrans_kernel(
    const float* __restrict__ W, u16* __restrict__ Wt, int K, int M) {
  __shared__ float tile[32][33];
  int m0 = blockIdx.x * 32, k0 = blockIdx.y * 32;
  const float* Wz = W + (size_t)blockIdx.z * K * M;
  u16* Wtz = Wt + (size_t)blockIdx.z * K * M;
  int x = threadIdx.x & 31, y = threadIdx.x >> 5;
  #pragma unroll
  for (int i = 0; i < 32; i += 8)
    tile[y + i][x] = Wz[(size_t)(k0 + y + i) * M + m0 + x];
  __syncthreads();
  #pragma unroll
  for (int i = 0; i < 32; i += 8)
    Wtz[(size_t)(m0 + y + i) * K + k0 + x] = f2b(tile[x][y + i]);
}

// ---------------------------------------------------------------------------
// V transpose: vb bf16 [B,Skv,512] -> vT bf16 [B*H,128,Skv]. grid (Skv/32,4,BH)
__global__ __launch_bounds__(256) void vtrans_kernel(
    const u16* __restrict__ vb, u16* __restrict__ vT, int Skv) {
  __shared__ u16 tile[32][33];
  int kv0 = blockIdx.x * 32, d0 = blockIdx.y * 32;
  int z = blockIdx.z, b = z >> 2, h = z & 3;
  const u16* src = vb + ((size_t)b * Skv) * 512 + h * 128;
  u16* dst = vT + (size_t)z * 128 * Skv;
  int x = threadIdx.x & 31, y = threadIdx.x >> 5;
  #pragma unroll
  for (int i = 0; i < 32; i += 8)
    tile[y + i][x] = src[(size_t)(kv0 + y + i) * 512 + d0 + x];
  __syncthreads();
  #pragma unroll
  for (int i = 0; i < 32; i += 8)
    dst[(size_t)(d0 + y + i) * Skv + kv0 + x] = tile[x][y + i];
}

// ---------------------------------------------------------------------------
// softmax rows: S fp32 [rows,L] -> P bf16 (normalized). wave/row, block=256
__global__ __launch_bounds__(256) void softmax_kernel(
    const float* __restrict__ S, u16* __restrict__ P, int L) {
  int wave = threadIdx.x >> 6, lane = threadIdx.x & 63;
  int row = blockIdx.x * 4 + wave;
  const float* sr = S + (size_t)row * L;
  u16* pr = P + (size_t)row * L;
  const float scale = 0.08838834764831845f;  // 1/sqrt(128)
  float mx = -1e30f;
  for (int j = lane; j < L; j += 64) mx = fmaxf(mx, sr[j]);
  #pragma unroll
  for (int off = 32; off; off >>= 1) mx = fmaxf(mx, __shfl_xor(mx, off, 64));
  float e[16];
  int cnt = L >> 6;
  float sum = 0.f;
  for (int c = 0; c < cnt; ++c) {
    e[c] = __expf((sr[lane + (c << 6)] - mx) * scale);
    sum += e[c];
  }
  #pragma unroll
  for (int off = 32; off; off >>= 1) sum += __shfl_xor(sum, off, 64);
  float inv = 1.0f / sum;
  for (int c = 0; c < cnt; ++c) pr[lane + (c << 6)] = f2b(e[c] * inv);
}

// ---------------------------------------------------------------------------
// MFMA 64x64 tile core. block=256 (4 waves, 2x2), BK=64, 16x16x32 bf16.
// A: bf16, row stride lda (pre-offset to tile). Wt: bf16 [col][k], stride ldw.
// LDS tiles XOR-swizzled: byte col ^= (row&7)<<4  (2-way max -> free).
__device__ __forceinline__ void mfma_core(
    const u16* __restrict__ A, int lda, const u16* __restrict__ Wt, int ldw,
    int K, u16* AsB, u16* WsB, f32x4 acc[2][2]) {
  int t = threadIdx.x;
  int lane = t & 63, wave = t >> 6;
  int wr = (wave >> 1) * 32, wc = (wave & 1) * 32;
  int lrow = t >> 3;      // 0..31
  int lseg = t & 7;       // 16B segment
  int swz = (lseg * 16) ^ ((lrow & 7) << 4);
  const u16* Ap0 = A + (size_t)lrow * lda + lseg * 8;
  const u16* Ap1 = Ap0 + (size_t)32 * lda;
  const u16* Wp0 = Wt + (size_t)lrow * ldw + lseg * 8;
  const u16* Wp1 = Wp0 + (size_t)32 * ldw;
  for (int k0 = 0; k0 < K; k0 += 64) {
    uint4 a0 = *(const uint4*)(Ap0 + k0);
    uint4 a1 = *(const uint4*)(Ap1 + k0);
    uint4 w0 = *(const uint4*)(Wp0 + k0);
    uint4 w1 = *(const uint4*)(Wp1 + k0);
    __syncthreads();
    *(uint4*)((char*)AsB + lrow * 128 + swz) = a0;
    *(uint4*)((char*)AsB + (lrow + 32) * 128 + swz) = a1;
    *(uint4*)((char*)WsB + lrow * 128 + swz) = w0;
    *(uint4*)((char*)WsB + (lrow + 32) * 128 + swz) = w1;
    __syncthreads();
    #pragma unroll
    for (int ks = 0; ks < 2; ++ks) {
      bf16x8 af[2], bfr[2];
      #pragma unroll
      for (int mi = 0; mi < 2; ++mi) {
        int row = wr + mi * 16 + (lane & 15);
        int cb = (ks * 64 + ((lane >> 4) << 4)) ^ ((row & 7) << 4);
        af[mi] = *(const bf16x8*)((const char*)AsB + row * 128 + cb);
      }
      #pragma unroll
      for (int ni = 0; ni < 2; ++ni) {
        int row = wc + ni * 16 + (lane & 15);
        int cb = (ks * 64 + ((lane >> 4) << 4)) ^ ((row & 7) << 4);
        bfr[ni] = *(const bf16x8*)((const char*)WsB + row * 128 + cb);
      }
      #pragma unroll
      for (int mi = 0; mi < 2; ++mi)
        #pragma unroll
        for (int ni = 0; ni < 2; ++ni)
          acc[mi][ni] = __builtin_amdgcn_mfma_f32_16x16x32_bf16(
              af[mi], bfr[ni], acc[mi][ni], 0, 0, 0);
    }
  }
}

// ---------------------------------------------------------------------------
// generic GEMM: C = act(A @ Wt^T + bias). flags: 1=GELU 2=RES 4=outF 8=outB
__global__ __launch_bounds__(256) void gemm_k(
    const u16* __restrict__ A, int lda, const u16* __restrict__ Wt, int ldw,
    int K, const float* __restrict__ bias, float* __restrict__ Cf,
    u16* __restrict__ Cb, int ldc, int flags) {
  __shared__ u16 As[4096], Ws[4096];
  int n0 = blockIdx.y * 64, m0 = blockIdx.x * 64;
  f32x4 acc[2][2];
  #pragma unroll
  for (int i = 0; i < 2; ++i)
    #pragma unroll
    for (int j = 0; j < 2; ++j) acc[i][j] = (f32x4){0.f, 0.f, 0.f, 0.f};
  mfma_core(A + (size_t)n0 * lda, lda, Wt + (size_t)m0 * ldw, ldw, K, As, Ws, acc);
  int lane = threadIdx.x & 63, wave = threadIdx.x >> 6;
  int wr = (wave >> 1) * 32, wc = (wave & 1) * 32;
  #pragma unroll
  for (int mi = 0; mi < 2; ++mi) {
    #pragma unroll
    for (int ni = 0; ni < 2; ++ni) {
      int col = m0 + wc + ni * 16 + (lane & 15);
      float bv = bias[col];
      #pragma unroll
      for (int j = 0; j < 4; ++j) {
        int row = n0 + wr + mi * 16 + ((lane >> 4) << 2) + j;
        float v = acc[mi][ni][j] + bv;
        if (flags & 1) v = gelu_exact(v);
        size_t idx = (size_t)row * ldc + col;
        if (flags & 2) v += Cf[idx];
        if (flags & 4) Cf[idx] = v;
        if (flags & 8) Cb[idx] = f2b(v);
      }
    }
  }
}

// ---------------------------------------------------------------------------
// scores: S[bh,Sq,Skv] = Q @ K^T (bf16 in, fp32 out). grid (Skv/64,Sq/64,BH)
__global__ __launch_bounds__(256) void scores_k(
    const u16* __restrict__ Qb, const u16* __restrict__ Kb,
    float* __restrict__ S, int Sq, int Skv) {
  __shared__ u16 As[4096], Ws[4096];
  int z = blockIdx.z, b = z >> 2, h = z & 3;
  int n0 = blockIdx.y * 64, m0 = blockIdx.x * 64;
  const u16* Ap = Qb + ((size_t)b * Sq + n0) * 512 + h * 128;
  const u16* Wp = Kb + ((size_t)b * Skv + m0) * 512 + h * 128;
  f32x4 acc[2][2];
  #pragma unroll
  for (int i = 0; i < 2; ++i)
    #pragma unroll
    for (int j = 0; j < 2; ++j) acc[i][j] = (f32x4){0.f, 0.f, 0.f, 0.f};
  mfma_core(Ap, 512, Wp, 512, 128, As, Ws, acc);
  float* Sz = S + (size_t)z * Sq * Skv;
  int lane = threadIdx.x & 63, wave = threadIdx.x >> 6;
  int wr = (wave >> 1) * 32, wc = (wave & 1) * 32;
  #pragma unroll
  for (int mi = 0; mi < 2; ++mi)
    #pragma unroll
    for (int ni = 0; ni < 2; ++ni) {
      int col = m0 + wc + ni * 16 + (lane & 15);
      #pragma unroll
      for (int j = 0; j < 4; ++j) {
        int row = n0 + wr + mi * 16 + ((lane >> 4) << 2) + j;
        Sz[(size_t)row * Skv + col] = acc[mi][ni][j];
      }
    }
}

// ---------------------------------------------------------------------------
// PV: O[b,q,h*128+d] (bf16) = P[bh] @ V^T[bh]. grid (2, Sq/64, BH)
__global__ __launch_bounds__(256) void pv_k(
    const u16* __restrict__ P, const u16* __restrict__ vT,
    u16* __restrict__ O, int Sq, int Skv) {
  __shared__ u16 As[4096], Ws[4096];
  int z = blockIdx.z, b = z >> 2, h = z & 3;
  int n0 = blockIdx.y * 64, m0 = blockIdx.x * 64;
  const u16* Ap = P + (size_t)z * Sq * Skv + (size_t)n0 * Skv;
  const u16* Wp = vT + (size_t)z * 128 * Skv + (size_t)m0 * Skv;
  f32x4 acc[2][2];
  #pragma unroll
  for (int i = 0; i < 2; ++i)
    #pragma unroll
    for (int j = 0; j < 2; ++j) acc[i][j] = (f32x4){0.f, 0.f, 0.f, 0.f};
  mfma_core(Ap, Skv, Wp, Skv, Skv, As, Ws, acc);
  int lane = threadIdx.x & 63, wave = threadIdx.x >> 6;
  int wr = (wave >> 1) * 32, wc = (wave & 1) * 32;
  #pragma unroll
  for (int mi = 0; mi < 2; ++mi)
    #pragma unroll
    for (int ni = 0; ni < 2; ++ni) {
      int col = m0 + wc + ni * 16 + (lane & 15);
      #pragma unroll
      for (int j = 0; j < 4; ++j) {
        int row = n0 + wr + mi * 16 + ((lane >> 4) << 2) + j;
        O[((size_t)b * Sq + row) * 512 + h * 128 + col] = f2b(acc[mi][ni][j]);
      }
    }
}

// ---------------------------------------------------------------------------
extern "C" void kernel_launch(void* const* d_in, const int* in_sizes, int n_in,
                              void* d_out, int out_size, void* d_ws, size_t ws_size,
                              hipStream_t stream) {
  (void)in_sizes; (void)n_in; (void)out_size; (void)ws_size;
  const float* h_bytes  = (const float*)d_in[0];
  const int*   b0       = (const int*)d_in[1];
  const int*   b1       = (const int*)d_in[2];
  const int*   b2       = (const int*)d_in[3];
  const float* mlp_ln_g = (const float*)d_in[4];
  const float* mlp_ln_b = (const float*)d_in[5];
  const float* mlp_w1   = (const float*)d_in[6];
  const float* mlp_b1   = (const float*)d_in[7];
  const float* mlp_w2   = (const float*)d_in[8];
  const float* mlp_b2   = (const float*)d_in[9];
  const float* ca_w     = (const float*)d_in[10];
  const float* ca_b     = (const float*)d_in[11];
  const float* ca_ln_g  = (const float*)d_in[12];
  const float* ca_ln_b  = (const float*)d_in[13];

  float* out0 = (float*)d_out;
  float* out1 = out0 + 4 * 1024 * 512;
  float* out2 = out1 + 4 * 256 * 512;

  char* wsb = (char*)d_ws;
  // persistent bf16 weights: 14 MB
  u16* w1t = (u16*)wsb;                       // [3][1024][512]
  u16* w2t = w1t + 3 * 524288;                // [3][512][1024]
  u16* cat = w2t + 3 * 524288;                // [2][8][512][512]
  u16*   lnbuf = (u16*)(wsb + (14u << 20));   // 4 MB
  u16*   hbuf  = (u16*)(wsb + (18u << 20));   // 8 MB (MLP phase)
  u16*   qb    = (u16*)(wsb + (18u << 20));   // 4 MB (cross)
  u16*   kb    = (u16*)(wsb + (22u << 20));   // 4 MB
  u16*   Pbuf  = (u16*)(wsb + (18u << 20));   // 8 MB, overlays qb+kb (dead)
  u16*   vT    = (u16*)(wsb + (26u << 20));   // 4 MB
  u16*   vb    = (u16*)(wsb + (30u << 20));   // 4 MB
  u16*   ccbf  = (u16*)(wsb + (34u << 20));   // 4 MB
  float* Sbuf  = (float*)(wsb + (30u << 20)); // 16 MB, overlays vb+ccbf (dead)
  u16*   abuf  = (u16*)(wsb + (46u << 20));   // 4 MB
  int* starts0 = (int*)(wsb + (50u << 20));
  int* starts1 = starts0 + 4096;
  int* starts2 = starts1 + 1024;

  // ---- weight cast+transpose (bf16, [M,K])
  wtrans_kernel<<<dim3(32, 16, 3), 256, 0, stream>>>(mlp_w1, w1t, 512, 1024);
  wtrans_kernel<<<dim3(16, 32, 3), 256, 0, stream>>>(mlp_w2, w2t, 1024, 512);
  wtrans_kernel<<<dim3(16, 16, 16), 256, 0, stream>>>(ca_w, cat, 512, 512);

  scan_bounds_kernel<<<4, 1024, 0, stream>>>(b0, starts0, 8192, 1024);
  scan_bounds_kernel<<<4, 1024, 0, stream>>>(b1, starts1, 1024, 256);
  scan_bounds_kernel<<<4, 1024, 0, stream>>>(b2, starts2, 256, 64);

  // ---- levels: pool + MLP
  auto mlp = [&](float* X, int Ntok, int lvl) {
    ln_kernel<<<Ntok / 4, 256, 0, stream>>>(X, mlp_ln_g + lvl * 512,
                                            mlp_ln_b + lvl * 512, lnbuf, Ntok);
    gemm_k<<<dim3(16, Ntok / 64), 256, 0, stream>>>(
        lnbuf, 512, w1t + (size_t)lvl * 524288, 512, 512,
        mlp_b1 + lvl * 1024, nullptr, hbuf, 1024, 1 | 8);
    gemm_k<<<dim3(8, Ntok / 64), 256, 0, stream>>>(
        hbuf, 1024, w2t + (size_t)lvl * 524288, 1024, 1024,
        mlp_b2 + lvl * 512, X, nullptr, 512, 2 | 4);
  };
  pool_kernel<<<dim3(1024, 4), 128, 0, stream>>>(h_bytes, starts0, out0, 8192, 1024);
  mlp(out0, 4096, 0);
  pool_kernel<<<dim3(256, 4), 128, 0, stream>>>(out0, starts1, out1, 1024, 256);
  mlp(out1, 1024, 1);
  pool_kernel<<<dim3(64, 4), 128, 0, stream>>>(out1, starts2, out2, 256, 64);
  mlp(out2, 256, 2);

  // ---- cross-level refinement
  auto cross = [&](int i, float* F, float* Cc, int nf, int nc) {
    u16* cw = cat + (size_t)i * 8 * 262144;
    const float* bb = ca_b + (size_t)i * 8 * 512;
    const float* lg = ca_ln_g + (size_t)i * 2 * 512;
    const float* lb = ca_ln_b + (size_t)i * 2 * 512;
    int Nf = 4 * nf, Nc = 4 * nc;
    // bottom-up: q = ln(F), kv = Cc
    ln_kernel<<<Nf / 4, 256, 0, stream>>>(F, lg, lb, lnbuf, Nf);
    gemm_k<<<dim3(8, Nf / 64), 256, 0, stream>>>(lnbuf, 512, cw, 512, 512,
                                                 bb, nullptr, qb, 512, 8);
    castbf_kernel<<<Nc / 4, 256, 0, stream>>>(Cc, ccbf, Nc * 64);
    gemm_k<<<dim3(8, Nc / 64), 256, 0, stream>>>(ccbf, 512, cw + 262144, 512, 512,
                                                 bb + 512, nullptr, kb, 512, 8);
    gemm_k<<<dim3(8, Nc / 64), 256, 0, stream>>>(ccbf, 512, cw + 2 * 262144, 512, 512,
                                                 bb + 1024, nullptr, vb, 512, 8);
    vtrans_kernel<<<dim3(nc / 32, 4, 16), 256, 0, stream>>>(vb, vT, nc);
    scores_k<<<dim3(nc / 64, nf / 64, 16), 256, 0, stream>>>(qb, kb, Sbuf, nf, nc);
    softmax_kernel<<<16 * nf / 4, 256, 0, stream>>>(Sbuf, Pbuf, nc);
    pv_k<<<dim3(2, nf / 64, 16), 256, 0, stream>>>(Pbuf, vT, abuf, nf, nc);
    gemm_k<<<dim3(8, Nf / 64), 256, 0, stream>>>(abuf, 512, cw + 3 * 262144, 512, 512,
                                                 bb + 3 * 512, F, nullptr, 512, 2 | 4);
    // top-down: q = ln(Cc), kv = updated F
    ln_kernel<<<Nc / 4, 256, 0, stream>>>(Cc, lg + 512, lb + 512, lnbuf, Nc);
    gemm_k<<<dim3(8, Nc / 64), 256, 0, stream>>>(lnbuf, 512, cw + 4 * 262144, 512, 512,
                                                 bb + 4 * 512, nullptr, qb, 512, 8);
    castbf_kernel<<<Nf / 4, 256, 0, stream>>>(F, ccbf, Nf * 64);
    gemm_k<<<dim3(8, Nf / 64), 256, 0, stream>>>(ccbf, 512, cw + 5 * 262144, 512, 512,
                                                 bb + 5 * 512, nullptr, kb, 512, 8);
    gemm_k<<<dim3(8, Nf / 64), 256, 0, stream>>>(ccbf, 512, cw + 6 * 262144, 512, 512,
                                                 bb + 6 * 512, nullptr, vb, 512, 8);
    vtrans_kernel<<<dim3(nf / 32, 4, 16), 256, 0, stream>>>(vb, vT, nf);
    scores_k<<<dim3(nf / 64, nc / 64, 16), 256, 0, stream>>>(qb, kb, Sbuf, nc, nf);
    softmax_kernel<<<16 * nc / 4, 256, 0, stream>>>(Sbuf, Pbuf, nf);
    pv_k<<<dim3(2, nc / 64, 16), 256, 0, stream>>>(Pbuf, vT, abuf, nc, nf);
    gemm_k<<<dim3(8, Nc / 64), 256, 0, stream>>>(abuf, 512, cw + 7 * 262144, 512, 512,
                                                 bb + 7 * 512, Cc, nullptr, 512, 2 | 4);
  };
  cross(1, out1, out2, 256, 64);
  cross(0, out0, out1, 1024, 256);
}